// Round 11
// baseline (59.377 us; speedup 1.0000x reference)
//
#include <hip/hip_runtime.h>
#include <hip/hip_bf16.h>

#define NSPEC 4
#define NFEAT 144
#define RCUT 5.0f
#define RPB 64                 // centers per bucket / accum block
#define MAXB 1568              // max buckets (NC <= 100352)
#define CAP 1536               // pairs capacity per bucket (avg ~1178, +10 sigma)
#define CHUNK 8192             // pairs per partition block
#define PBDIM 1024             // partdest block threads (16 waves)
#define IPT (CHUNK / PBDIM)    // items per thread = 8
#define ABDIM 512              // accum block threads (8 waves, 2 per bin)
#define ASTRIDE 148            // accum stage stride (floats)
#define LDSN (CHUNK + 2 * MAXB + 16 + 64)

// ---------- utility ----------

__global__ void zero_f32(float* __restrict__ out, int n) {
    int n4 = n >> 2;
    float4* o4 = (float4*)out;
    for (int i = blockIdx.x * blockDim.x + threadIdx.x; i < n4; i += gridDim.x * blockDim.x)
        o4[i] = make_float4(0.f, 0.f, 0.f, 0.f);
    int tail = n & 3;
    if (blockIdx.x == 0 && threadIdx.x < tail) out[n4 * 4 + threadIdx.x] = 0.f;
}

// ---------- prep: per-chunk species counts + gCursor zeroing ----------

__global__ void prep_kernel(const int* __restrict__ cs, int n, int* __restrict__ chunkCounts,
                            int* __restrict__ zeroPtr, int zeroN) {
    __shared__ int cnt[NSPEC];
    if (threadIdx.x < NSPEC) cnt[threadIdx.x] = 0;
    __syncthreads();
    int i = blockIdx.x * blockDim.x + threadIdx.x;
    if (i < n) atomicAdd(&cnt[cs[i]], 1);
    if (zeroPtr) {
        for (int j = i; j < zeroN; j += gridDim.x * blockDim.x) zeroPtr[j] = 0;
    }
    __syncthreads();
    if (threadIdx.x < NSPEC) chunkCounts[blockIdx.x * NSPEC + threadIdx.x] = cnt[threadIdx.x];
}

// ---------- fused partition + dest kernel ----------
// blocks [0, nPart):      partition pairs into center-block buckets
// blocks [nPart, +nChunks): compute dest[] for one 256-center chunk (redundant reduce)
// payload u: bits[31:8] = r (low 8 mantissa bits replaced), bits[7:2] = center&63,
// bits[1:0] = species.

__global__ void __launch_bounds__(PBDIM) partdest_kernel(
        const float* __restrict__ dirs, const int* __restrict__ pci,
        const int* __restrict__ nsi, const int* __restrict__ cs,
        const int* __restrict__ chunkCounts, int* __restrict__ dest,
        int* __restrict__ gCursor, unsigned* __restrict__ gBucket,
        int P, int NC, int nbk, int nChunks, int nPart) {
    __shared__ int ldsraw[LDSN];

    int tid = threadIdx.x;

    if ((int)blockIdx.x < nPart) {
        // ---------------- partition job ----------------
        unsigned* sSort = (unsigned*)ldsraw;          // CHUNK
        int* sHist = ldsraw + CHUNK;                  // MAXB
        int* sOffs = sHist + MAXB;                    // MAXB
        int* sWaveTot = sOffs + MAXB;                 // 16

        int base = blockIdx.x * CHUNK;

        for (int i = tid; i < nbk; i += PBDIM) sHist[i] = 0;
        __syncthreads();

        unsigned uu[IPT];
        int bb[IPT];
        #pragma unroll
        for (int j = 0; j < IPT; ++j) {
            int i = base + j * PBDIM + tid;
            int bkt = -1; unsigned u = 0;
            if (i < P) {
                float x = dirs[3 * i + 0], y = dirs[3 * i + 1], z = dirs[3 * i + 2];
                float r2 = x * x + y * y + z * z;
                if (r2 < RCUT * RCUT) {
                    float r = sqrtf(r2);
                    int c = pci[i];
                    bkt = c >> 6;
                    u = (__float_as_uint(r) & 0xFFFFFF00u) | ((unsigned)(c & 63) << 2) |
                        (unsigned)nsi[i];
                    atomicAdd(&sHist[bkt], 1);
                }
            }
            uu[j] = u; bb[j] = bkt;
        }
        __syncthreads();

        // block exclusive scan of sHist[0..nbk) into sOffs
        int seg = (nbk + PBDIM - 1) / PBDIM;
        int s0 = tid * seg;
        int run = 0;
        for (int k = 0; k < seg; ++k) {
            int idx = s0 + k;
            if (idx < nbk) { sOffs[idx] = run; run += sHist[idx]; }
        }
        int lane = tid & 63, wv = tid >> 6;
        int incl = run;
        #pragma unroll
        for (int off = 1; off < 64; off <<= 1) {
            int t = __shfl_up(incl, off);
            if (lane >= off) incl += t;
        }
        if (lane == 63) sWaveTot[wv] = incl;
        __syncthreads();
        int wbase = 0;
        for (int w = 0; w < wv; ++w) wbase += sWaveTot[w];
        int exc = wbase + incl - run;
        for (int k = 0; k < seg; ++k) {
            int idx = s0 + k;
            if (idx < nbk) sOffs[idx] += exc;
        }
        __syncthreads();

        // scatter into LDS sorted order (sOffs becomes end-cursor per bucket)
        #pragma unroll
        for (int j = 0; j < IPT; ++j) {
            if (bb[j] >= 0) {
                int pos = atomicAdd(&sOffs[bb[j]], 1);
                sSort[pos] = uu[j];
            }
        }
        __syncthreads();

        // flush each bucket's contiguous run to its global region
        for (int b = tid; b < nbk; b += PBDIM) {
            int c = sHist[b];
            if (!c) continue;
            int start = sOffs[b] - c;
            int g = atomicAdd(&gCursor[b], c);
            int lim = min(c, CAP - g);      // safety clamp
            unsigned* dst = gBucket + (size_t)b * CAP + g;
            for (int k = 0; k < lim; ++k) dst[k] = sSort[start + k];
        }
    } else {
        // ---------------- dest job: chunk cj ----------------
        int cj = blockIdx.x - nPart;
        if (cj >= nChunks) return;
        int* red   = ldsraw;        // 8: pref[4], tot[4]
        int* cOffs = ldsraw + 8;    // 4
        int* wCnt  = ldsraw + 12;   // 16*4

        if (tid < 8) red[tid] = 0;
        __syncthreads();

        int nCE = nChunks * NSPEC;
        for (int idx = tid; idx < nCE; idx += PBDIM) {
            int c = idx >> 2, s = idx & 3;
            int v = chunkCounts[idx];
            if (v) {
                if (c < cj) atomicAdd(&red[s], v);
                atomicAdd(&red[4 + s], v);
            }
        }
        __syncthreads();

        if (tid == 0) {
            int b = 0;
            #pragma unroll
            for (int s = 0; s < NSPEC; ++s) { cOffs[s] = b + red[s]; b += red[4 + s]; }
        }
        __syncthreads();

        // ballot rank for the 256 centers of this chunk (threads 0-255 active)
        int i = cj * 256 + tid;
        int s = (tid < 256 && i < NC) ? cs[i] : -1;
        int lane = tid & 63, wv = tid >> 6;
        int lanePrefix = 0;
        #pragma unroll
        for (int sp = 0; sp < NSPEC; ++sp) {
            unsigned long long b = __ballot(s == sp);
            if (lane == 0) wCnt[wv * 4 + sp] = __popcll(b);
            if (sp == s) lanePrefix = __popcll(b & ((1ull << lane) - 1ull));
        }
        __syncthreads();
        if (s >= 0) {
            int wp = 0;
            for (int w = 0; w < wv; ++w) wp += wCnt[w * 4 + s];
            dest[i] = cOffs[s] + wp + lanePrefix;
        }
    }
}

// ---------- accumulate: bucket -> LDS sort -> TWO threads per (center,species) bin ----------

__global__ void __launch_bounds__(ABDIM) accum_kernel(
        const int* __restrict__ gCursor, const unsigned* __restrict__ gBucket,
        const int* __restrict__ dest, float* __restrict__ out, int NC) {
    __shared__ unsigned sSort[CAP];
    __shared__ int sHist[256];
    __shared__ int sOff[256];
    __shared__ int sWaveTot[ABDIM / 64];
    __shared__ int destLds[RPB];
    __shared__ float sStage[RPB * ASTRIDE];

    int tid = threadIdx.x;
    int b = blockIdx.x;
    int cBase = b * RPB;
    int n = min(gCursor[b], CAP);
    const unsigned* src = gBucket + (size_t)b * CAP;

    if (tid < 256) sHist[tid] = 0;
    if (tid < RPB && cBase + tid < NC) destLds[tid] = dest[cBase + tid];
    __syncthreads();

    // pass 1: histogram (bucket tiny; second read below hits L2)
    for (int i = tid; i < n; i += ABDIM) atomicAdd(&sHist[src[i] & 255u], 1);
    __syncthreads();

    // exclusive scan of 256 bins (threads 0-255 = waves 0-3)
    int lane = tid & 63, wv = tid >> 6;
    int v = 0, incl = 0;
    if (tid < 256) {
        v = sHist[tid];
        incl = v;
        #pragma unroll
        for (int off = 1; off < 64; off <<= 1) {
            int t = __shfl_up(incl, off);
            if (lane >= off) incl += t;
        }
        if (lane == 63) sWaveTot[wv] = incl;
    }
    __syncthreads();
    if (tid < 256) {
        int wbase = 0;
        for (int w = 0; w < wv; ++w) wbase += sWaveTot[w];
        sOff[tid] = wbase + incl - v;
    }
    __syncthreads();

    // pass 2: scatter into LDS sorted order (sOff becomes end-cursor)
    for (int i = tid; i < n; i += ABDIM) {
        unsigned u = src[i];
        int pos = atomicAdd(&sOff[u & 255u], 1);
        sSort[pos] = u;
    }
    __syncthreads();

    // bin k = tid>>1 = (centerLocal<<2)|species; sub-lane tid&1 takes every other pair
    int k = tid >> 1, sub = tid & 1;
    int end = sOff[k], start = end - sHist[k];
    float acc[36];
    #pragma unroll
    for (int j = 0; j < 36; ++j) acc[j] = 0.f;

    for (int p = start + sub; p < end; p += 2) {
        unsigned u = sSort[p];
        float r = __uint_as_float(u & 0xFFFFFF00u);
        float r2 = r * r;
        float fc = 0.5f * (__cosf(0.6283185307179586f * r) + 1.0f);  // cos(pi*r/RCUT)
        float q = __expf(-r2 * 0.04f);                                // exp(-r^2/25)
        float q2 = q * q;
        float bq[12];  // bq[n] = q^(n+1), two independent x q^2 chains
        bq[0] = q; bq[1] = q2;
        #pragma unroll
        for (int nn = 2; nn < 12; ++nn) bq[nn] = bq[nn - 2] * q2;
        float a0 = fc, a1 = fc * r, a2 = a1 * r, a3 = a2 * r;
        #pragma unroll
        for (int nn = 0; nn < 12; ++nn) acc[nn]      = fmaf(a0, bq[nn], acc[nn]);
        #pragma unroll
        for (int nn = 0; nn < 10; ++nn) acc[12 + nn] = fmaf(a1, bq[nn], acc[12 + nn]);
        #pragma unroll
        for (int nn = 0; nn < 8; ++nn)  acc[22 + nn] = fmaf(a2, bq[nn], acc[22 + nn]);
        #pragma unroll
        for (int nn = 0; nn < 6; ++nn)  acc[30 + nn] = fmaf(a3, bq[nn], acc[30 + nn]);
    }

    // merge the two sub-lanes (adjacent lanes in the same wave)
    #pragma unroll
    for (int j = 0; j < 36; ++j) acc[j] += __shfl_xor(acc[j], 1);

    // stage in [row][col] layout: row = k>>2, col = off_l + 4n + (k&3)
    if (sub == 0) {
        float* rowp = sStage + (k >> 2) * ASTRIDE + (k & 3);
        #pragma unroll
        for (int nn = 0; nn < 12; ++nn) rowp[nn * 4]       = acc[nn];
        #pragma unroll
        for (int nn = 0; nn < 10; ++nn) rowp[48 + nn * 4]  = acc[12 + nn];
        #pragma unroll
        for (int nn = 0; nn < 8; ++nn)  rowp[88 + nn * 4]  = acc[22 + nn];
        #pragma unroll
        for (int nn = 0; nn < 6; ++nn)  rowp[120 + nn * 4] = acc[30 + nn];
    }
    __syncthreads();

    // write out: 36 float4 per row, row -> out[dest[center]]
    int nRows = min(RPB, NC - cBase);
    int lim = nRows * 36;
    for (int i = tid; i < lim; i += ABDIM) {
        int row = i / 36;
        int c4 = i - row * 36;
        float4 val = *(const float4*)(sStage + row * ASTRIDE + c4 * 4);
        *(float4*)(out + (size_t)destLds[row] * NFEAT + c4 * 4) = val;
    }
}

// ---------- fallback: direct atomic scatter ----------

__global__ void pair_kernel(const float* __restrict__ dirs,
                            const int* __restrict__ pci,
                            const int* __restrict__ nsi,
                            const int* __restrict__ dest,
                            float* __restrict__ out, int P) {
    int i = blockIdx.x * blockDim.x + threadIdx.x;
    if (i >= P) return;
    float x = dirs[3 * i + 0], y = dirs[3 * i + 1], z = dirs[3 * i + 2];
    float r2 = x * x + y * y + z * z;
    float r = sqrtf(r2);
    if (r >= RCUT) return;
    float fc = 0.5f * (cosf(3.14159265358979323846f * r * (1.0f / RCUT)) + 1.0f);
    float q = expf(-r2 * (1.0f / (RCUT * RCUT)));
    int rowb = dest[pci[i]] * NFEAT;
    int s = nsi[i];
    float* o = out + rowb + s;
    float rl = fc;
    const int nmax[4] = {12, 10, 8, 6};
    const int offl[4] = {0, 48, 88, 120};
    #pragma unroll
    for (int l = 0; l < 4; ++l) {
        float e = q;
        for (int n = 0; n < nmax[l]; ++n) { atomicAdd(o + offl[l] + n * NSPEC, rl * e); e *= q; }
        rl *= r;
    }
}

extern "C" void kernel_launch(void* const* d_in, const int* in_sizes, int n_in,
                              void* d_out, int out_size, void* d_ws, size_t ws_size,
                              hipStream_t stream) {
    const float* dirs = (const float*)d_in[0];
    const int* pci = (const int*)d_in[1];
    const int* nsi = (const int*)d_in[2];
    const int* cs = (const int*)d_in[3];
    int P = in_sizes[1];
    int NC = in_sizes[3];
    float* out = (float*)d_out;

    int nChunks = (NC + 255) / 256;
    int nbk = (NC + RPB - 1) / RPB;
    int nPart = (P + CHUNK - 1) / CHUNK;

    // ws layout (ints)
    int* chunkCounts  = (int*)d_ws;                      // nChunks*4
    int* dest         = chunkCounts + nChunks * NSPEC;   // NC
    int* gCursor      = dest + NC;                       // nbk
    unsigned* gBucket = (unsigned*)(gCursor + nbk);      // nbk*CAP

    size_t need = ((size_t)(nChunks * NSPEC) + (size_t)NC + (size_t)nbk +
                   (size_t)nbk * CAP) * sizeof(int);
    bool fastPath = (ws_size >= need) && (nbk <= MAXB);

    if (fastPath) {
        prep_kernel<<<nChunks, 256, 0, stream>>>(cs, NC, chunkCounts, gCursor, nbk);
        partdest_kernel<<<nPart + nChunks, PBDIM, 0, stream>>>(
            dirs, pci, nsi, cs, chunkCounts, dest, gCursor, gBucket,
            P, NC, nbk, nChunks, nPart);
        accum_kernel<<<nbk, ABDIM, 0, stream>>>(gCursor, gBucket, dest, out, NC);
    } else {
        // fallback: prep + dest-only partdest + atomic pair scatter
        prep_kernel<<<nChunks, 256, 0, stream>>>(cs, NC, chunkCounts, (int*)nullptr, 0);
        partdest_kernel<<<nChunks, PBDIM, 0, stream>>>(
            dirs, pci, nsi, cs, chunkCounts, dest, (int*)d_ws /*unused*/, (unsigned*)d_ws,
            0 /*P=0 -> no partition blocks*/, NC, nbk, nChunks, 0);
        zero_f32<<<2048, 256, 0, stream>>>(out, out_size);
        pair_kernel<<<(P + 255) / 256, 256, 0, stream>>>(dirs, pci, nsi, dest, out, P);
    }
}